// Round 1
// baseline (367.871 us; speedup 1.0000x reference)
//
#include <hip/hip_runtime.h>
#include <hip/hip_bf16.h>
#include <cstdint>
#include <cstddef>

#define NROWS 8192
#define MCOLS 8192
#define DDIM  512
#define GRP   10

using f32x4 = __attribute__((ext_vector_type(4))) float;

typedef const __attribute__((address_space(1))) void* gas_ptr;
typedef __attribute__((address_space(3))) void* las_ptr;

// ---------------------------------------------------------------------------
// Kernel 1 (unchanged): cast fp32 rows -> fp8 e4m3 + per-row sum of squares.
// Block 2*NROWS computes the 10x10 group tables (t, c2) as float2.
// ---------------------------------------------------------------------------
__global__ __launch_bounds__(256) void prep_all(const float* __restrict__ X,
                                                const float* __restrict__ Z,
                                                uint16_t* __restrict__ Xa,
                                                uint16_t* __restrict__ Za,
                                                float* __restrict__ xx,
                                                float* __restrict__ zz,
                                                const float* __restrict__ emb,
                                                const float* __restrict__ sigma_p,
                                                const float* __restrict__ ls_p,
                                                const float* __restrict__ gdp_p,
                                                float2* __restrict__ tab) {
    int row = blockIdx.x;
    int t = threadIdx.x;
    if (row == 2 * NROWS) {            // table block
        if (t >= GRP * GRP) return;
        int a = t / GRP, b = t % GRP;
        float gd = 0.0f;
        #pragma unroll
        for (int g = 0; g < GRP; ++g) {
            float d = emb[a * GRP + g] - emb[b * GRP + g];
            gd += d * d;
        }
        float val = 1.0f / (fabsf(*gdp_p) * gd + 1.0f);
        float ls = *ls_p;
        float sg = *sigma_p;
        tab[t] = make_float2(-0.5f * val / (ls * ls),
                             sg * sg * powf(val, 0.5f * (float)DDIM));
        return;
    }
    const float* src;
    uint16_t* dst;
    float* sums;
    int r;
    if (row < NROWS) {
        r = row; src = X + (size_t)r * DDIM; dst = Xa + (size_t)r * (DDIM / 2); sums = xx;
    } else {
        r = row - NROWS; src = Z + (size_t)r * DDIM; dst = Za + (size_t)r * (DDIM / 2); sums = zz;
    }
    float2 p = ((const float2*)src)[t];          // 8B/lane coalesced
    int packed = __builtin_amdgcn_cvt_pk_fp8_f32(p.x, p.y, 0, false);
    dst[t] = (uint16_t)packed;                   // 2B/lane coalesced
    float s = p.x * p.x + p.y * p.y;
    #pragma unroll
    for (int off = 32; off > 0; off >>= 1) s += __shfl_down(s, off, 64);
    __shared__ float ws[4];
    if ((t & 63) == 0) ws[t >> 6] = s;
    __syncthreads();
    if (t == 0) sums[r] = ws[0] + ws[1] + ws[2] + ws[3];
}

// ---------------------------------------------------------------------------
// Kernel 2: fp8 MFMA GEMM (X @ Z^T) + fused MGGP-RBF epilogue.
// 256x256 tile, 8 waves (2Mx4N, each wave 128x64), BK=128 bytes, 16 phases
// straight-line (DDIM/BK = 4 K-tiles x 4 kk each), T3+T4+T5 schedule:
//   phase = { ds_read frags (1 kk) | stage 1 half-tile | barrier |
//             lgkmcnt(0) | setprio(1) 32 MFMA setprio(0) | [vmcnt(N)] barrier }
// LDS 128 KiB: per matrix 4 slots [buf][kh][256 rows][64 B] (K-half slots so
// staging halves are CONTIGUOUS for global_load_lds).
// Sync ledger (halves h = kt*4+kh*2+mat, 2 loads each; prologue h0..h5):
//   phase P<=9 stages h=6+P.  End-of-odd-phase waits:
//   P1,3,5,7,9 -> vmcnt(8); P11 -> vmcnt(4); P13 -> vmcnt(0).
//   Slot re-stage issue is always >=1 phase after its last read (safe), and
//   each consumed half is retired by the wait one phase before its reads.
// Swizzle both-sides (rule 21): source chunk pc = c ^ ((r>>1)&3), reader
// granule pg = g ^ (((m>>1)&3)<<1) -> ds_read_b64 hits exactly 4/bank (b64
// minimum, conflict-free).
// ---------------------------------------------------------------------------
__global__ __launch_bounds__(512, 2) void mggp_gemm(
    const uint8_t* __restrict__ Xa, const uint8_t* __restrict__ Za,
    const float* __restrict__ xx, const float* __restrict__ zz,
    const int* __restrict__ gX, const int* __restrict__ gZ,
    const float2* __restrict__ tab,
    float* __restrict__ out) {

    extern __shared__ __align__(16) uint8_t lds[];   // 131072 B dynamic

    const int tid  = threadIdx.x;
    const int lane = tid & 63;
    const int w    = tid >> 6;       // wave 0..7
    const int wr   = w >> 2;         // wave row (0..1)  -> 128 rows each
    const int wc   = w & 3;          // wave col (0..3)  -> 64 cols each
    const int m    = lane & 15;
    const int q    = lane >> 4;      // k-octet quad

    // 16x16 supertile remap over the 32x32 block grid (XCD L2 locality)
    const int lin = blockIdx.x;
    const int st  = lin >> 6;        // 0..15
    const int wi  = lin & 63;
    const int bx  = (st & 3) * 8 + (wi & 7);
    const int by  = (st >> 2) * 8 + (wi >> 3);
    const int brow = by * 256;
    const int bcol = bx * 256;

    // stage one half (A or B) of K-half kh of K-tile skt into its LDS slot
    auto stageA = [&](int skt, int skh) {
        const int slot = ((skt & 1) * 2 + skh) * 16384;
        #pragma unroll
        for (int l = 0; l < 2; ++l) {
            int s = l * 512 + tid;           // 16B chunk index 0..1023
            int r = s >> 2;                  // tile row 0..255
            int pc = (s & 3) ^ ((r >> 1) & 3);
            const uint8_t* src = Xa + (size_t)(brow + r) * DDIM + skt * 128 + skh * 64 + pc * 16;
            __builtin_amdgcn_global_load_lds((gas_ptr)src, (las_ptr)(lds + slot + s * 16), 16, 0, 0);
        }
    };
    auto stageB = [&](int skt, int skh) {
        const int slot = 65536 + ((skt & 1) * 2 + skh) * 16384;
        #pragma unroll
        for (int l = 0; l < 2; ++l) {
            int s = l * 512 + tid;
            int r = s >> 2;
            int pc = (s & 3) ^ ((r >> 1) & 3);
            const uint8_t* src = Za + (size_t)(bcol + r) * DDIM + skt * 128 + skh * 64 + pc * 16;
            __builtin_amdgcn_global_load_lds((gas_ptr)src, (las_ptr)(lds + slot + s * 16), 16, 0, 0);
        }
    };

    f32x4 acc[8][4];
    #pragma unroll
    for (int ti = 0; ti < 8; ++ti)
        #pragma unroll
        for (int tj = 0; tj < 4; ++tj)
            #pragma unroll
            for (int e = 0; e < 4; ++e) acc[ti][tj][e] = 0.0f;

    // ---- prologue: halves h0..h5 = kt0(A/B kh0, A/B kh1), kt1(A/B kh0) ----
    stageA(0, 0); stageB(0, 0);
    stageA(0, 1); stageB(0, 1);
    stageA(1, 0); stageB(1, 0);
    asm volatile("s_waitcnt vmcnt(8)" ::: "memory");   // h0,h1 landed
    __builtin_amdgcn_s_barrier();

    // reader swizzle, invariant across ti/tj (f(r) = (m>>1)&3 since ti*16 ≡ 0 mod 8)
    const int f2m = ((m >> 1) & 3) << 1;

    #pragma unroll
    for (int P = 0; P < 16; ++P) {
        const int kt  = P >> 2;
        const int kk  = P & 3;
        const int buf = kt & 1;
        const int kh  = kk >> 1;
        const int kl  = kk & 1;
        const int slotA = (buf * 2 + kh) * 16384;
        const int slotB = 65536 + slotA;
        const int pgl = ((kl * 4 + q) ^ f2m) * 8;      // physical 8B granule

        const uint8_t* abase = lds + slotA + (wr * 128 + m) * 64 + pgl;
        const uint8_t* bbase = lds + slotB + (wc * 64 + m) * 64 + pgl;
        long aF[8], bF[4];
        #pragma unroll
        for (int ti = 0; ti < 8; ++ti) aF[ti] = *(const long*)(abase + ti * 1024);
        #pragma unroll
        for (int tj = 0; tj < 4; ++tj) bF[tj] = *(const long*)(bbase + tj * 1024);

        // stage half h = 6+P (P<=9): issue is >=1 phase after slot's last read
        if (P <= 9) {
            const int h   = 6 + P;
            const int skt = h >> 2;
            const int skh = (h >> 1) & 1;
            if ((h & 1) == 0) stageA(skt, skh); else stageB(skt, skh);
        }

        __builtin_amdgcn_s_barrier();
        asm volatile("s_waitcnt lgkmcnt(0)" ::: "memory");
        __builtin_amdgcn_sched_barrier(0);             // rule 18: pin MFMA after wait

        __builtin_amdgcn_s_setprio(1);
        #pragma unroll
        for (int ti = 0; ti < 8; ++ti)
            #pragma unroll
            for (int tj = 0; tj < 4; ++tj)
                acc[ti][tj] = __builtin_amdgcn_mfma_f32_16x16x32_fp8_fp8(
                    aF[ti], bF[tj], acc[ti][tj], 0, 0, 0);
        __builtin_amdgcn_s_setprio(0);

        // counted vmcnt at odd-phase ends (protects next phase's slot pair)
        if (P == 1 || P == 3 || P == 5 || P == 7 || P == 9)
            asm volatile("s_waitcnt vmcnt(8)" ::: "memory");
        else if (P == 11)
            asm volatile("s_waitcnt vmcnt(4)" ::: "memory");
        else if (P == 13)
            asm volatile("s_waitcnt vmcnt(0)" ::: "memory");
        __builtin_amdgcn_s_barrier();
    }

    // ---- epilogue: K = c2[ga][gb] * exp(dist * t[ga][gb]) ----
    float zzv[4];
    int   gbv[4];
    #pragma unroll
    for (int tj = 0; tj < 4; ++tj) {
        int j = bcol + wc * 64 + tj * 16 + m;   // C/D: col = lane&15
        zzv[tj] = zz[j];
        gbv[tj] = gZ[j];
    }
    #pragma unroll
    for (int ti = 0; ti < 8; ++ti) {
        #pragma unroll
        for (int rg = 0; rg < 4; ++rg) {
            int i = brow + wr * 128 + ti * 16 + q * 4 + rg;  // C/D: row = quad*4+reg
            float xxi = xx[i];
            int   ga  = gX[i] * GRP;
            float* orow = out + (size_t)i * MCOLS + bcol + wc * 64 + m;
            #pragma unroll
            for (int tj = 0; tj < 4; ++tj) {
                float dot  = acc[ti][tj][rg];
                float dist = xxi + zzv[tj] - 2.0f * dot;
                float2 tc  = tab[ga + gbv[tj]];
                orow[tj * 16] = tc.y * __expf(dist * tc.x);
            }
        }
    }
}

// ---------------------------------------------------------------------------
extern "C" void kernel_launch(void* const* d_in, const int* in_sizes, int n_in,
                              void* d_out, int out_size, void* d_ws, size_t ws_size,
                              hipStream_t stream) {
    const float* X     = (const float*)d_in[0];
    const float* Z     = (const float*)d_in[1];
    const int*   gX    = (const int*)d_in[2];
    const int*   gZ    = (const int*)d_in[3];
    const float* emb   = (const float*)d_in[4];
    const float* sigma = (const float*)d_in[5];
    const float* ls    = (const float*)d_in[6];
    const float* gdp   = (const float*)d_in[7];

    char* ws = (char*)d_ws;
    const size_t XA_OFF  = 0;                              // 8192*512 = 4 MiB
    const size_t ZA_OFF  = XA_OFF + (size_t)NROWS * DDIM;  // 4 MiB
    const size_t XX_OFF  = ZA_OFF + (size_t)MCOLS * DDIM;
    const size_t ZZ_OFF  = XX_OFF + (size_t)NROWS * 4;
    const size_t TAB_OFF = ZZ_OFF + (size_t)MCOLS * 4;

    uint8_t* Xa  = (uint8_t*)(ws + XA_OFF);
    uint8_t* Za  = (uint8_t*)(ws + ZA_OFF);
    float* xx    = (float*)(ws + XX_OFF);
    float* zz    = (float*)(ws + ZZ_OFF);
    float2* tab  = (float2*)(ws + TAB_OFF);

    static bool inited = false;
    if (!inited) {
        // ROCm generally allows dynamic LDS up to the 160 KiB HW max; set the
        // attribute anyway for safety and ignore any error (not a stream op).
        (void)hipFuncSetAttribute((const void*)mggp_gemm,
                                  hipFuncAttributeMaxDynamicSharedMemorySize, 131072);
        inited = true;
    }

    prep_all<<<2 * NROWS + 1, 256, 0, stream>>>(X, Z, (uint16_t*)Xa, (uint16_t*)Za,
                                                xx, zz, emb, sigma, ls, gdp, tab);
    mggp_gemm<<<1024, 512, 131072, stream>>>(Xa, Za, xx, zz, gX, gZ, tab, (float*)d_out);
}

// Round 2
// 354.082 us; speedup vs baseline: 1.0389x; 1.0389x over previous
//
#include <hip/hip_runtime.h>
#include <hip/hip_bf16.h>
#include <cstdint>
#include <cstddef>

#define NROWS 8192
#define MCOLS 8192
#define DDIM  512
#define GRP   10

using f32x4 = __attribute__((ext_vector_type(4))) float;
using i64x2 = __attribute__((ext_vector_type(2))) long;

typedef const __attribute__((address_space(1))) void* gas_ptr;
typedef __attribute__((address_space(3))) void* las_ptr;

// ---------------------------------------------------------------------------
// Kernel 1: cast fp32 rows -> fp8 e4m3 + per-row sum of squares.
// NEW: k-bytes are stored PRE-PERMUTED per 64-byte k-tile so the GEMM's
// fragment reads are 16B-contiguous (ds_read_b128):
//   logical granule g = kk*4+q  ->  physical granule P = q*2+kk
// (dot product is k-permutation invariant since A and B share the order).
// Block 2*NROWS computes the 10x10 group tables (t, c2) as float2.
// ---------------------------------------------------------------------------
__global__ __launch_bounds__(256) void prep_all(const float* __restrict__ X,
                                                const float* __restrict__ Z,
                                                uint16_t* __restrict__ Xa,
                                                uint16_t* __restrict__ Za,
                                                float* __restrict__ xx,
                                                float* __restrict__ zz,
                                                const float* __restrict__ emb,
                                                const float* __restrict__ sigma_p,
                                                const float* __restrict__ ls_p,
                                                const float* __restrict__ gdp_p,
                                                float2* __restrict__ tab) {
    int row = blockIdx.x;
    int t = threadIdx.x;
    if (row == 2 * NROWS) {            // table block
        if (t >= GRP * GRP) return;
        int a = t / GRP, b = t % GRP;
        float gd = 0.0f;
        #pragma unroll
        for (int g = 0; g < GRP; ++g) {
            float d = emb[a * GRP + g] - emb[b * GRP + g];
            gd += d * d;
        }
        float val = 1.0f / (fabsf(*gdp_p) * gd + 1.0f);
        float ls = *ls_p;
        float sg = *sigma_p;
        tab[t] = make_float2(-0.5f * val / (ls * ls),
                             sg * sg * powf(val, 0.5f * (float)DDIM));
        return;
    }
    const float* src;
    uint16_t* dst;
    float* sums;
    int r;
    if (row < NROWS) {
        r = row; src = X + (size_t)r * DDIM; dst = Xa + (size_t)r * (DDIM / 2); sums = xx;
    } else {
        r = row - NROWS; src = Z + (size_t)r * DDIM; dst = Za + (size_t)r * (DDIM / 2); sums = zz;
    }
    float2 p = ((const float2*)src)[t];          // 8B/lane coalesced
    int packed = __builtin_amdgcn_cvt_pk_fp8_f32(p.x, p.y, 0, false);
    // permuted store: logical byte b=2t -> phys = kt*64 + (q*2+kk)*8 + off
    int b    = 2 * t;                            // 0..510, even
    int g    = (b >> 3) & 7;                     // granule in 64B k-tile
    int P    = ((g & 3) << 1) | (g >> 2);        // q*2 + kk
    int phys = (b & 0x1C0) | (P << 3) | (b & 7);
    dst[phys >> 1] = (uint16_t)packed;
    float s = p.x * p.x + p.y * p.y;
    #pragma unroll
    for (int off = 32; off > 0; off >>= 1) s += __shfl_down(s, off, 64);
    __shared__ float ws[4];
    if ((t & 63) == 0) ws[t >> 6] = s;
    __syncthreads();
    if (t == 0) sums[r] = ws[0] + ws[1] + ws[2] + ws[3];
}

// ---------------------------------------------------------------------------
// Kernel 2: fp8 MFMA GEMM (X @ Z^T) + fused MGGP-RBF epilogue.
// 256x256 tile, 8 waves (2Mx4N, wave = 128x64), BK=64, 8 phases (1/K-tile):
//   phase = { 12x ds_read_b128 | stage(kt+2): 4x global_load_lds | barrier |
//             setprio(1) 64 MFMA setprio(0) | vmcnt(4) | barrier }
// Triple-buffered LDS 96 KiB (3 bufs x 16 KiB x {A,B}); stage 2 tiles ahead
// -> ~2 MFMA-phases (~2500 cyc) of load-latency cover; vmcnt never drains
// to 0 until the tail (kt=6). No sched_barrier / no asm lgkm: plain ds_reads
// let the compiler emit staged lgkmcnt (m97/m141 lessons).
// LDS row = 64 B = 4 chunks of 16 B. Read chunk for lane (q,m) = q^((r>>1)&3);
// with the prep permutation each chunk holds both K=32 fragments for octet q.
// Bank check: every 16B chunk-column gets exactly 8 of 64 lanes -> 1024 B in
// the 8-cycle minimum (conflict-free-equivalent for b128).
// Stage source pre-applies the same XOR on the global chunk (rule 21: LDS
// dest of global_load_lds stays linear).
// ---------------------------------------------------------------------------
__global__ __launch_bounds__(512, 2) void mggp_gemm(
    const uint8_t* __restrict__ Xa, const uint8_t* __restrict__ Za,
    const float* __restrict__ xx, const float* __restrict__ zz,
    const int* __restrict__ gX, const int* __restrict__ gZ,
    const float2* __restrict__ tab,
    float* __restrict__ out) {

    extern __shared__ __align__(16) uint8_t lds[];   // 98304 B dynamic

    const int tid  = threadIdx.x;
    const int lane = tid & 63;
    const int w    = tid >> 6;       // wave 0..7
    const int wr   = w >> 2;         // wave row (0..1) -> 128 rows
    const int wc   = w & 3;          // wave col (0..3) -> 64 cols
    const int m    = lane & 15;
    const int q    = lane >> 4;      // k-octet quad

    // per-XCD square supertiles: each XCD owns an 8(by) x 16(bx) region
    // -> resident working set per XCD L2 ~ 2 A-panels + 16 B-panels ~ 2.3 MB
    const int lin = blockIdx.x;
    const int xcd = lin & 7;
    const int i0  = lin >> 3;        // 0..127
    const int by  = (xcd >> 1) * 8 + (i0 >> 4);
    const int bx  = (xcd & 1) * 16 + (i0 & 15);
    const int brow = by * 256;
    const int bcol = bx * 256;

    // stage one 256x64 tile (16 KiB) of matrix kt into LDS buffer at ldsoff
    auto stage = [&](const uint8_t* __restrict__ base, int rowoff, int kt, int ldsoff) {
        #pragma unroll
        for (int l = 0; l < 2; ++l) {
            int s  = l * 512 + tid;              // 16B chunk 0..1023 (linear dest)
            int r  = s >> 2;                     // tile row 0..255
            int cg = (s & 3) ^ ((r >> 1) & 3);   // pre-swizzled global chunk
            const uint8_t* src = base + (size_t)(rowoff + r) * DDIM + kt * 64 + cg * 16;
            __builtin_amdgcn_global_load_lds((gas_ptr)src, (las_ptr)(lds + ldsoff + s * 16), 16, 0, 0);
        }
    };

    f32x4 acc[8][4];
    #pragma unroll
    for (int ti = 0; ti < 8; ++ti)
        #pragma unroll
        for (int tj = 0; tj < 4; ++tj)
            #pragma unroll
            for (int e = 0; e < 4; ++e) acc[ti][tj][e] = 0.0f;

    // prologue: stage kt=0 and kt=1 (8 loads/wave), wait for kt=0 (oldest 4)
    stage(Xa, brow, 0, 0);
    stage(Za, bcol, 0, 49152);
    stage(Xa, brow, 1, 16384);
    stage(Za, bcol, 1, 49152 + 16384);
    asm volatile("s_waitcnt vmcnt(4)" ::: "memory");
    __builtin_amdgcn_s_barrier();

    // lane-invariant read offsets (swizzle (r>>1)&3 reduces to (m>>1)&3)
    const int swz  = (m >> 1) & 3;
    const int aoff = (wr * 128 + m) * 64 + ((q ^ swz) * 16);
    const int boff = (wc * 64 + m) * 64 + ((q ^ swz) * 16);

    #pragma unroll
    for (int kt = 0; kt < 8; ++kt) {
        const int bi   = kt % 3;
        const int abuf = bi * 16384;
        const int bbuf = 49152 + bi * 16384;

        i64x2 aF[8], bF[4];
        #pragma unroll
        for (int ti = 0; ti < 8; ++ti)
            aF[ti] = *(const i64x2*)(lds + abuf + aoff + ti * 1024);
        #pragma unroll
        for (int tj = 0; tj < 4; ++tj)
            bF[tj] = *(const i64x2*)(lds + bbuf + boff + tj * 1024);

        if (kt <= 5) {                 // stage kt+2 into buf[(kt+2)%3]
            const int bn = (kt + 2) % 3;
            stage(Xa, brow, kt + 2, bn * 16384);
            stage(Za, bcol, kt + 2, 49152 + bn * 16384);
        }

        __builtin_amdgcn_s_barrier();

        __builtin_amdgcn_s_setprio(1);
        #pragma unroll
        for (int kk = 0; kk < 2; ++kk)
            #pragma unroll
            for (int ti = 0; ti < 8; ++ti)
                #pragma unroll
                for (int tj = 0; tj < 4; ++tj)
                    acc[ti][tj] = __builtin_amdgcn_mfma_f32_16x16x32_fp8_fp8(
                        aF[ti][kk], bF[tj][kk], acc[ti][tj], 0, 0, 0);
        __builtin_amdgcn_s_setprio(0);

        // counted waits: steady state keeps stage(kt+2) (4 loads) in flight
        if (kt <= 5)      asm volatile("s_waitcnt vmcnt(4)" ::: "memory");
        else if (kt == 6) asm volatile("s_waitcnt vmcnt(0)" ::: "memory");
        if (kt < 7) __builtin_amdgcn_s_barrier();
    }

    // ---- epilogue: K = c2[ga][gb] * exp(dist * t[ga][gb]) ----
    float zzv[4];
    int   gbv[4];
    #pragma unroll
    for (int tj = 0; tj < 4; ++tj) {
        int j = bcol + wc * 64 + tj * 16 + m;   // C/D: col = lane&15
        zzv[tj] = zz[j];
        gbv[tj] = gZ[j];
    }
    #pragma unroll
    for (int ti = 0; ti < 8; ++ti) {
        #pragma unroll
        for (int rg = 0; rg < 4; ++rg) {
            int i = brow + wr * 128 + ti * 16 + q * 4 + rg;  // C/D: row = quad*4+reg
            float xxi = xx[i];
            int   ga  = gX[i] * GRP;
            float* orow = out + (size_t)i * MCOLS + bcol + wc * 64 + m;
            #pragma unroll
            for (int tj = 0; tj < 4; ++tj) {
                float dot  = acc[ti][tj][rg];
                float dist = xxi + zzv[tj] - 2.0f * dot;
                float2 tc  = tab[ga + gbv[tj]];
                orow[tj * 16] = tc.y * __expf(dist * tc.x);
            }
        }
    }
}

// ---------------------------------------------------------------------------
extern "C" void kernel_launch(void* const* d_in, const int* in_sizes, int n_in,
                              void* d_out, int out_size, void* d_ws, size_t ws_size,
                              hipStream_t stream) {
    const float* X     = (const float*)d_in[0];
    const float* Z     = (const float*)d_in[1];
    const int*   gX    = (const int*)d_in[2];
    const int*   gZ    = (const int*)d_in[3];
    const float* emb   = (const float*)d_in[4];
    const float* sigma = (const float*)d_in[5];
    const float* ls    = (const float*)d_in[6];
    const float* gdp   = (const float*)d_in[7];

    char* ws = (char*)d_ws;
    const size_t XA_OFF  = 0;                              // 8192*512 = 4 MiB
    const size_t ZA_OFF  = XA_OFF + (size_t)NROWS * DDIM;  // 4 MiB
    const size_t XX_OFF  = ZA_OFF + (size_t)MCOLS * DDIM;
    const size_t ZZ_OFF  = XX_OFF + (size_t)NROWS * 4;
    const size_t TAB_OFF = ZZ_OFF + (size_t)MCOLS * 4;

    uint8_t* Xa  = (uint8_t*)(ws + XA_OFF);
    uint8_t* Za  = (uint8_t*)(ws + ZA_OFF);
    float* xx    = (float*)(ws + XX_OFF);
    float* zz    = (float*)(ws + ZZ_OFF);
    float2* tab  = (float2*)(ws + TAB_OFF);

    static bool inited = false;
    if (!inited) {
        (void)hipFuncSetAttribute((const void*)mggp_gemm,
                                  hipFuncAttributeMaxDynamicSharedMemorySize, 98304);
        inited = true;
    }

    prep_all<<<2 * NROWS + 1, 256, 0, stream>>>(X, Z, (uint16_t*)Xa, (uint16_t*)Za,
                                                xx, zz, emb, sigma, ls, gdp, tab);
    mggp_gemm<<<1024, 512, 98304, stream>>>(Xa, Za, xx, zz, gX, gZ, tab, (float*)d_out);
}

// Round 3
// 340.689 us; speedup vs baseline: 1.0798x; 1.0393x over previous
//
#include <hip/hip_runtime.h>
#include <hip/hip_bf16.h>
#include <cstdint>
#include <cstddef>

#define NROWS 8192
#define MCOLS 8192
#define DDIM  512
#define GRP   10

using f32x16 = __attribute__((ext_vector_type(16))) float;
using i32x4  = __attribute__((ext_vector_type(4))) int;
using i32x8  = __attribute__((ext_vector_type(8))) int;

typedef const __attribute__((address_space(1))) void* gas_ptr;
typedef __attribute__((address_space(3))) void* las_ptr;

// ---------------------------------------------------------------------------
// Kernel 1: cast fp32 rows -> fp8 e4m3 (linear k-order) + per-row sum of
// squares. Block 2*NROWS computes the 10x10 group tables (t, c2) as float2.
// ---------------------------------------------------------------------------
__global__ __launch_bounds__(256) void prep_all(const float* __restrict__ X,
                                                const float* __restrict__ Z,
                                                uint16_t* __restrict__ Xa,
                                                uint16_t* __restrict__ Za,
                                                float* __restrict__ xx,
                                                float* __restrict__ zz,
                                                const float* __restrict__ emb,
                                                const float* __restrict__ sigma_p,
                                                const float* __restrict__ ls_p,
                                                const float* __restrict__ gdp_p,
                                                float2* __restrict__ tab) {
    int row = blockIdx.x;
    int t = threadIdx.x;
    if (row == 2 * NROWS) {            // table block
        if (t >= GRP * GRP) return;
        int a = t / GRP, b = t % GRP;
        float gd = 0.0f;
        #pragma unroll
        for (int g = 0; g < GRP; ++g) {
            float d = emb[a * GRP + g] - emb[b * GRP + g];
            gd += d * d;
        }
        float val = 1.0f / (fabsf(*gdp_p) * gd + 1.0f);
        float ls = *ls_p;
        float sg = *sigma_p;
        tab[t] = make_float2(-0.5f * val / (ls * ls),
                             sg * sg * powf(val, 0.5f * (float)DDIM));
        return;
    }
    const float* src;
    uint16_t* dst;
    float* sums;
    int r;
    if (row < NROWS) {
        r = row; src = X + (size_t)r * DDIM; dst = Xa + (size_t)r * (DDIM / 2); sums = xx;
    } else {
        r = row - NROWS; src = Z + (size_t)r * DDIM; dst = Za + (size_t)r * (DDIM / 2); sums = zz;
    }
    float2 p = ((const float2*)src)[t];          // 8B/lane coalesced
    int packed = __builtin_amdgcn_cvt_pk_fp8_f32(p.x, p.y, 0, false);
    dst[t] = (uint16_t)packed;                   // 2B/lane coalesced, linear
    float s = p.x * p.x + p.y * p.y;
    #pragma unroll
    for (int off = 32; off > 0; off >>= 1) s += __shfl_down(s, off, 64);
    __shared__ float ws[4];
    if ((t & 63) == 0) ws[t >> 6] = s;
    __syncthreads();
    if (t == 0) sums[r] = ws[0] + ws[1] + ws[2] + ws[3];
}

// ---------------------------------------------------------------------------
// Kernel 2: MX-scaled fp8 MFMA GEMM (X @ Z^T) + fused MGGP-RBF epilogue.
// R0's proven 128x128 / 4-wave / 2-barrier structure, with the compute core
// swapped to v_mfma_scale_f32_32x32x64_f8f6f4 (unit e8m0 scales = 0x7F):
// plain fp8 GEMM at 2x the non-scaled rate (m148: 995->1628 TF for this
// exact swap), 4x fewer MFMA issue slots, half the fragment-read instrs.
// Each wave: 64x64 out as 2x2 of 32x32, K=64 per MFMA, BK=128 (2 kk steps).
// LDS row = 128 B = 8 chunks of 16 B, chunk XOR swizzle (R0): phys chunk
// p = logical c ^ (r&7), applied on the GLOBAL source (LDS dest of
// global_load_lds stays linear, rule 21). Fragment read for (ti,kk): lane
// (cl=lane&31, hi=lane>>5) reads 32 B = chunks {c1, c1^1}, c1 = (kk*4+hi*2)
// ^ (r&7) -> per b128: 8 lanes per chunk-column, uniform over 32 banks =
// 8-clk minimum (conflict-free).
// (256,3): ~115 live VGPR (acc 64 + frags 32 + addr), cap 170, 3 blocks/CU
// -> cross-block overlap hides barriers + epilogue (m114).
// ---------------------------------------------------------------------------
__global__ __launch_bounds__(256, 3) void mggp_gemm(
    const uint8_t* __restrict__ Xa, const uint8_t* __restrict__ Za,
    const float* __restrict__ xx, const float* __restrict__ zz,
    const int* __restrict__ gX, const int* __restrict__ gZ,
    const float2* __restrict__ tab,
    float* __restrict__ out) {

    __shared__ __align__(16) uint8_t Al[128 * 128];   // 16 KB
    __shared__ __align__(16) uint8_t Bl[128 * 128];   // 16 KB

    const int tid  = threadIdx.x;
    const int lane = tid & 63;
    const int w    = tid >> 6;       // wave 0..3
    const int wr   = w >> 1;         // wave row (0..1)
    const int wc   = w & 1;          // wave col (0..1)
    const int cl   = lane & 31;      // col/row within 32-tile
    const int hi   = lane >> 5;      // k-half selector

    // 8x8 supertile remap (consecutive ids round-robin XCDs)
    const int lin = blockIdx.x;
    const int st  = lin >> 6;
    const int wi  = lin & 63;
    const int bx  = (st & 7) * 8 + (wi & 7);
    const int by  = (st >> 3) * 8 + (wi >> 3);
    const int brow = by * 128;
    const int bcol = bx * 128;

    f32x16 acc[2][2];
    #pragma unroll
    for (int ti = 0; ti < 2; ++ti)
        #pragma unroll
        for (int tj = 0; tj < 2; ++tj)
            #pragma unroll
            for (int e = 0; e < 16; ++e) acc[ti][tj][e] = 0.0f;

    for (int kt = 0; kt < DDIM / 128; ++kt) {
        __syncthreads();   // previous iter's LDS reads done before overwrite
        #pragma unroll
        for (int p = 0; p < 4; ++p) {
            int sbase = (w * 4 + p) * 64;       // slot = 16 B; 1024 slots/matrix
            int s = sbase + lane;
            int r = s >> 3;                     // tile row 0..127
            int c = (s & 7) ^ (r & 7);          // pre-swizzled global 16B chunk
            const uint8_t* ga = Xa + (size_t)(brow + r) * DDIM + kt * 128 + c * 16;
            __builtin_amdgcn_global_load_lds((gas_ptr)ga, (las_ptr)&Al[sbase * 16], 16, 0, 0);
            const uint8_t* gb = Za + (size_t)(bcol + r) * DDIM + kt * 128 + c * 16;
            __builtin_amdgcn_global_load_lds((gas_ptr)gb, (las_ptr)&Bl[sbase * 16], 16, 0, 0);
        }
        __syncthreads();   // vmcnt(0) drain before s_barrier

        #pragma unroll
        for (int kk = 0; kk < 2; ++kk) {
            i32x8 aF[2], bF[2];
            #pragma unroll
            for (int ti = 0; ti < 2; ++ti) {
                int r  = wr * 64 + ti * 32 + cl;
                int c1 = (kk * 4 + hi * 2) ^ (r & 7);
                i32x4 lo = *(const i32x4*)&Al[r * 128 + c1 * 16];
                i32x4 h4 = *(const i32x4*)&Al[r * 128 + (c1 ^ 1) * 16];
                aF[ti] = __builtin_shufflevector(lo, h4, 0, 1, 2, 3, 4, 5, 6, 7);
            }
            #pragma unroll
            for (int tj = 0; tj < 2; ++tj) {
                int r  = wc * 64 + tj * 32 + cl;
                int c1 = (kk * 4 + hi * 2) ^ (r & 7);
                i32x4 lo = *(const i32x4*)&Bl[r * 128 + c1 * 16];
                i32x4 h4 = *(const i32x4*)&Bl[r * 128 + (c1 ^ 1) * 16];
                bF[tj] = __builtin_shufflevector(lo, h4, 0, 1, 2, 3, 4, 5, 6, 7);
            }
            #pragma unroll
            for (int ti = 0; ti < 2; ++ti)
                #pragma unroll
                for (int tj = 0; tj < 2; ++tj)
                    acc[ti][tj] = __builtin_amdgcn_mfma_scale_f32_32x32x64_f8f6f4(
                        aF[ti], bF[tj], acc[ti][tj],
                        0, 0,                      // cbsz=fp8, blgp=fp8
                        0, 0x7F7F7F7F,             // opsel_a, scale_a = 1.0
                        0, 0x7F7F7F7F);            // opsel_b, scale_b = 1.0
        }
    }

    // ---- epilogue: K = c2[ga][gb] * exp(dist * t[ga][gb]) ----
    // C/D (32x32 shapes): col = lane&31, row = (reg&3) + 8*(reg>>2) + 4*hi
    float zzv[2];
    int   gbv[2];
    #pragma unroll
    for (int tj = 0; tj < 2; ++tj) {
        int j = bcol + wc * 64 + tj * 32 + cl;
        zzv[tj] = zz[j];
        gbv[tj] = gZ[j];
    }
    #pragma unroll
    for (int ti = 0; ti < 2; ++ti) {
        #pragma unroll
        for (int reg = 0; reg < 16; ++reg) {
            int i = brow + wr * 64 + ti * 32 + (reg & 3) + 8 * (reg >> 2) + 4 * hi;
            float xxi = xx[i];
            int   ga  = gX[i] * GRP;
            float* orow = out + (size_t)i * MCOLS + bcol + wc * 64 + cl;
            #pragma unroll
            for (int tj = 0; tj < 2; ++tj) {
                float dot  = acc[ti][tj][reg];
                float dist = xxi + zzv[tj] - 2.0f * dot;
                float2 tc  = tab[ga + gbv[tj]];
                orow[tj * 32] = tc.y * __expf(dist * tc.x);
            }
        }
    }
}

// ---------------------------------------------------------------------------
extern "C" void kernel_launch(void* const* d_in, const int* in_sizes, int n_in,
                              void* d_out, int out_size, void* d_ws, size_t ws_size,
                              hipStream_t stream) {
    const float* X     = (const float*)d_in[0];
    const float* Z     = (const float*)d_in[1];
    const int*   gX    = (const int*)d_in[2];
    const int*   gZ    = (const int*)d_in[3];
    const float* emb   = (const float*)d_in[4];
    const float* sigma = (const float*)d_in[5];
    const float* ls    = (const float*)d_in[6];
    const float* gdp   = (const float*)d_in[7];

    char* ws = (char*)d_ws;
    const size_t XA_OFF  = 0;                              // 8192*512 = 4 MiB
    const size_t ZA_OFF  = XA_OFF + (size_t)NROWS * DDIM;  // 4 MiB
    const size_t XX_OFF  = ZA_OFF + (size_t)MCOLS * DDIM;
    const size_t ZZ_OFF  = XX_OFF + (size_t)NROWS * 4;
    const size_t TAB_OFF = ZZ_OFF + (size_t)MCOLS * 4;

    uint8_t* Xa  = (uint8_t*)(ws + XA_OFF);
    uint8_t* Za  = (uint8_t*)(ws + ZA_OFF);
    float* xx    = (float*)(ws + XX_OFF);
    float* zz    = (float*)(ws + ZZ_OFF);
    float2* tab  = (float2*)(ws + TAB_OFF);

    prep_all<<<2 * NROWS + 1, 256, 0, stream>>>(X, Z, (uint16_t*)Xa, (uint16_t*)Za,
                                                xx, zz, emb, sigma, ls, gdp, tab);
    mggp_gemm<<<4096, 256, 0, stream>>>(Xa, Za, xx, zz, gX, gZ, tab, (float*)d_out);
}